// Round 6
// baseline (100.591 us; speedup 1.0000x reference)
//
#include <hip/hip_runtime.h>

// ParallelCNN: 4-branch masked conv bernoulli log-likelihood, B=16384, 28x28.
// Quad planes a=s[2i,2j], b=s[2i,2j+1], c=s[2i+1,2j], d=s[2i+1,2j+1].
// Branch pm pixels: b0->a (position-only logit), b1->d, b2->b, b3->c.
// R2->R3: removed __syncthreads in hot path + same-address atomics (48 -> ~15 us).
// R4: 2x occupancy NEUTRAL; R5: half the LDS ops (float2 image-pair fusion)
//     NEUTRAL -> main is ~9-12 us, near its HBM+LDS floor; remaining
//     controllable cost is the dispatch chain itself (~70 us of the window is
//     harness d_ws poison fill + input restore, confirmed by fill-dominated top-5).
// R6: 3 kernels -> 2. Position-logit tables computed cooperatively per block
//     into LDS (overlaid on planes storage; 4 pos_logits/thread one-time, two
//     one-time syncthreads) -- kills the prep dispatch + gap. Main writes
//     per-BLOCK partials (2048) so final reads 4x less.

#define GRID 2048   // 4 waves/block, 2 images/wave (float2-fused) -> 16384 images

__device__ __forceinline__ float sp_fast(float x) {
    // softplus; logits are small (|x| < ~3) so no range handling needed
    return __logf(1.0f + __expf(x));
}

// position-channel conv logit for branch x at pixel (h, ww), SAME zero pad
__device__ __forceinline__ float pos_logit(const float* __restrict__ pos,
                                           const float* __restrict__ w,
                                           const float* __restrict__ b,
                                           int x, int h, int ww) {
    float s = b[x];
    #pragma unroll
    for (int ky = 0; ky < 3; ++ky) {
        #pragma unroll
        for (int kx = 0; kx < 3; ++kx) {
            int hh = h + ky - 1, cc = ww + kx - 1;
            float p = (hh >= 0 && hh < 28 && cc >= 0 && cc < 28) ? pos[hh*28 + cc] : 0.0f;
            s = fmaf(w[x*18 + 9 + ky*3 + kx], p, s);   // weights[x][0][1][ky][kx]
        }
    }
    return s;
}

__global__ __launch_bounds__(256, 4)
void main_kernel(const float* __restrict__ samples,
                 const float* __restrict__ w,
                 const float* __restrict__ pos,
                 const float* __restrict__ b,
                 float* __restrict__ partial) {
    // wave-private planes, float2 entries = {img0, img1} per pixel.
    // 4 planes x 256 entries (16x16 with 1-elem zero halo). 8KB/wave, 32KB/block.
    // Hot path has NO __syncthreads: each wave touches only planes[wv];
    // same-wave DS ops are in-order; wave_barrier() pins compiler ordering.
    __shared__ float2 planes[4][1024];
    __shared__ float red[4];
    float* tbl = (float*)planes;    // one-time overlay: 980 floats, [s*196 + t]
    const int tid = threadIdx.x;
    const int wv = tid >> 6, ln = tid & 63;
    float2* myP = planes[wv];

    // ---- cooperative position-logit tables (one-time, replaces prep kernel) ----
    #pragma unroll
    for (int r = 0; r < 4; ++r) {
        int idx = r*256 + tid;
        if (idx < 980) {
            int s = idx / 196, t = idx - 196*s;
            int i = t / 14, j = t - 14*i;
            float val;
            if      (s == 0) val = pos_logit(pos, w, b, 0, 2*i,   2*j);
            else if (s == 1) val = sp_fast(pos_logit(pos, w, b, 0, 2*i, 2*j));
            else if (s == 2) val = pos_logit(pos, w, b, 1, 2*i+1, 2*j+1);
            else if (s == 3) val = pos_logit(pos, w, b, 2, 2*i,   2*j+1);
            else             val = pos_logit(pos, w, b, 3, 2*i+1, 2*j);
            tbl[idx] = val;
        }
    }
    __syncthreads();

    // sample-channel tap weights: weights[x][0][0][ky][kx] = w[x*18 + ky*3 + kx]
    const float w1a = w[18+0], w1b = w[18+2], w1c = w[18+6], w1d = w[18+8]; // b1 corners
    const float w2l = w[36+3], w2r = w[36+5], w2u = w[36+1], w2n = w[36+7]; // b2
    const float w3u = w[54+1], w3n = w[54+7], w3l = w[54+3], w3r = w[54+5]; // b3 a/d
    const float w3a = w[54+0], w3b = w[54+2], w3c = w[54+6], w3e = w[54+8]; // b3 corner b

    // per-lane quad tables (quads t = k*64 + lane) -> registers
    float C0[4], P1[4], P2[4], P3[4], S0s = 0.f;
    int oq[4], wo[4]; bool qv[4];
    #pragma unroll
    for (int k = 0; k < 4; ++k) {
        int t = k*64 + ln;
        qv[k] = (t < 196);
        int i = t / 14, j = t - 14*i;
        oq[k] = (i+1)*16 + (j+1);
        if (qv[k]) {
            C0[k] = tbl[t];        S0s  += tbl[196+t];
            P1[k] = tbl[392+t];    P2[k] = tbl[588+t];   P3[k] = tbl[784+t];
        } else { C0[k] = P1[k] = P2[k] = P3[k] = 0.f; }
        // float4 g covers row r=g/7, cols 4m..4m+3 -> parity de-interleave target
        int r = t / 7, m = t - 7*r;
        wo[k] = ((r & 1) ? 512 : 0) + ((r >> 1) + 1)*16 + 2*m + 1;
    }
    __syncthreads();   // all waves finished reading tbl before planes reuse

    // zero own planes (halo stays zero; interior rewritten below)
    #pragma unroll
    for (int z = 0; z < 8; ++z)
        ((float4*)myP)[z*64 + ln] = float4{0.f, 0.f, 0.f, 0.f};

    // branch-0 softplus term is image-independent: fold both images out
    float acc = -2.0f * S0s;
    const int img0 = blockIdx.x * 8 + wv * 2;
    const float4* src0 = (const float4*)(samples + (size_t)img0 * 784);
    const float4* src1 = (const float4*)(samples + (size_t)(img0 + 1) * 784);

    // load both images (8 float4 in flight), then one fused de-interleave fill
    float4 v0[4], v1[4];
    #pragma unroll
    for (int k = 0; k < 4; ++k)
        if (k < 3 || ln < 4) {                 // 196 float4 = 3*64 + 4
            v0[k] = src0[k*64 + ln];
            v1[k] = src1[k*64 + ln];
        }
    __builtin_amdgcn_wave_barrier();           // zero-init stays before writes
    #pragma unroll
    for (int k = 0; k < 4; ++k)
        if (k < 3 || ln < 4) {
            float2* p = myP + wo[k];
            p[0]   = float2{v0[k].x, v1[k].x};   // a/c plane, col j
            p[1]   = float2{v0[k].z, v1[k].z};   // a/c plane, col j+1
            p[256] = float2{v0[k].y, v1[k].y};   // b/d plane, col j
            p[257] = float2{v0[k].w, v1[k].w};   // b/d plane, col j+1
        }
    __builtin_amdgcn_wave_barrier();           // writes stay before reads

    // per-image quad log-likelihood
    auto quad_ll = [&](float a00, float a01, float a10, float a11,
                       float bl,  float bij, float bdl, float bdn,
                       float cij, float dup, float dl,  float dij,
                       float c0,  float p1,  float p2,  float p3) {
        // branch 0 (pixel a): logit = c0 const; softplus already folded
        acc = fmaf(a00, c0, acc);
        // branch 1 (pixel d): 4 a-corners
        float L1 = p1;
        L1 = fmaf(w1a, a00, L1); L1 = fmaf(w1b, a01, L1);
        L1 = fmaf(w1c, a10, L1); L1 = fmaf(w1d, a11, L1);
        acc += fmaf(dij, L1, -sp_fast(L1));
        // branch 2 (pixel b): horiz a, vert d
        float L2 = p2;
        L2 = fmaf(w2l, a00, L2); L2 = fmaf(w2r, a01, L2);
        L2 = fmaf(w2u, dup, L2); L2 = fmaf(w2n, dij, L2);
        acc += fmaf(bij, L2, -sp_fast(L2));
        // branch 3 (pixel c): vert a, horiz d, corner b
        float L3 = p3;
        L3 = fmaf(w3u, a00, L3); L3 = fmaf(w3n, a10, L3);
        L3 = fmaf(w3l, dl,  L3); L3 = fmaf(w3r, dij, L3);
        L3 = fmaf(w3a, bl,  L3); L3 = fmaf(w3b, bij, L3);
        L3 = fmaf(w3c, bdl, L3); L3 = fmaf(w3e, bdn, L3);
        acc += fmaf(cij, L3, -sp_fast(L3));
    };

    #pragma unroll
    for (int k = 0; k < 4; ++k) {
        if (qv[k]) {
            const int o = oq[k];
            float2 A00 = myP[o],        A01 = myP[o+1];
            float2 A10 = myP[o+16],     A11 = myP[o+17];
            float2 Bl  = myP[256+o-1],  Bij = myP[256+o];
            float2 Bdl = myP[256+o+15], Bdn = myP[256+o+16];
            float2 Cij = myP[512+o];
            float2 Dup = myP[768+o-16], Dl  = myP[768+o-1], Dij = myP[768+o];
            quad_ll(A00.x,A01.x,A10.x,A11.x, Bl.x,Bij.x,Bdl.x,Bdn.x,
                    Cij.x,Dup.x,Dl.x,Dij.x, C0[k],P1[k],P2[k],P3[k]);
            quad_ll(A00.y,A01.y,A10.y,A11.y, Bl.y,Bij.y,Bdl.y,Bdn.y,
                    Cij.y,Dup.y,Dl.y,Dij.y, C0[k],P1[k],P2[k],P3[k]);
        }
    }

    // wave butterfly -> per-block reduce -> ONE plain store per block
    #pragma unroll
    for (int off = 32; off >= 1; off >>= 1)
        acc += __shfl_xor(acc, off, 64);
    if (ln == 0) red[wv] = acc;
    __syncthreads();
    if (tid == 0) partial[blockIdx.x] = red[0] + red[1] + red[2] + red[3];
}

// reduce 2048 per-block partials -> out[0]; overwrites the 0xAA poison directly
__global__ void final_kernel(const float* __restrict__ partial,
                             float* __restrict__ out) {
    __shared__ float red[4];
    const int tid = threadIdx.x;
    float s = 0.f;
    #pragma unroll
    for (int i = 0; i < 8; ++i) s += partial[i*256 + tid];
    #pragma unroll
    for (int off = 32; off >= 1; off >>= 1) s += __shfl_xor(s, off, 64);
    if ((tid & 63) == 0) red[tid >> 6] = s;
    __syncthreads();
    if (tid == 0) out[0] = red[0] + red[1] + red[2] + red[3];
}

extern "C" void kernel_launch(void* const* d_in, const int* in_sizes, int n_in,
                              void* d_out, int out_size, void* d_ws, size_t ws_size,
                              hipStream_t stream) {
    const float* samples  = (const float*)d_in[0];
    const float* position = (const float*)d_in[1];
    const float* weights  = (const float*)d_in[2];
    const float* biases   = (const float*)d_in[3];
    float* partial = (float*)d_ws;   // 2048 floats
    float* out = (float*)d_out;

    main_kernel<<<GRID, 256, 0, stream>>>(samples, weights, position, biases, partial);
    final_kernel<<<1, 256, 0, stream>>>(partial, out);
}

// Round 7
// 95.638 us; speedup vs baseline: 1.0518x; 1.0518x over previous
//
#include <hip/hip_runtime.h>

// ParallelCNN: 4-branch masked conv bernoulli log-likelihood, B=16384, 28x28.
// Quad planes a=s[2i,2j], b=s[2i,2j+1], c=s[2i+1,2j], d=s[2i+1,2j+1].
// Branch pm pixels: b0->a (position-only logit), b1->d, b2->b, b3->c.
// Position-channel conv + bias -> per-quad tables, precomputed into d_ws.
//
// FINAL CONFIG = R3 (best measured: 95.4 us). Journal of later attempts, all
// reverted:
//   R4: __launch_bounds__(256,8) (2x residency)    -> NEUTRAL (main not TLP-bound)
//   R5: float2 image-pair fusion (half the LDS ops) -> NEUTRAL (LDS pipe not
//       the limiter at this scale)
//   R6: fuse prep into main + per-block partials    -> REGRESS +5us (per-block
//       recompute x2048 + 2 extra syncthreads cost more than one tiny dispatch)
// Floor arithmetic: window = harness d_ws 268MB poison fill (~42us) + samples
// restore (~16us) + fills/gaps (~10-15us) + prep ~2 + main ~10-12 (at its
// HBM/L3 floor; FETCH=25MB, half L3-resident) + final ~2  ~=  93-97us.
// Main kernel structure: wave-private LDS planes (no __syncthreads in hot
// path; same-wave DS ops are in-order), no atomics (per-wave plain stores).

#define GRID 2048   // 4 waves/block, 2 images/wave -> 16384 images exact

__device__ __forceinline__ float sp_fast(float x) {
    // softplus; logits are small (|x| < ~3) so no range handling needed
    return __logf(1.0f + __expf(x));
}

// position-channel conv logit for branch x at pixel (h, ww), SAME zero pad
__device__ __forceinline__ float pos_logit(const float* __restrict__ pos,
                                           const float* __restrict__ w,
                                           const float* __restrict__ b,
                                           int x, int h, int ww) {
    float s = b[x];
    #pragma unroll
    for (int ky = 0; ky < 3; ++ky) {
        #pragma unroll
        for (int kx = 0; kx < 3; ++kx) {
            int hh = h + ky - 1, cc = ww + kx - 1;
            float p = (hh >= 0 && hh < 28 && cc >= 0 && cc < 28) ? pos[hh*28 + cc] : 0.0f;
            s = fmaf(w[x*18 + 9 + ky*3 + kx], p, s);   // weights[x][0][1][ky][kx]
        }
    }
    return s;
}

// tbl layout: 8 floats per quad t: [C0, S0=softplus(C0), P1, P2, P3, 0, 0, 0]
__global__ void prep_kernel(const float* __restrict__ pos,
                            const float* __restrict__ w,
                            const float* __restrict__ b,
                            float* __restrict__ tbl) {
    int u = blockIdx.x * blockDim.x + threadIdx.x;   // 4 blocks x 256 = 1024
    int t = u >> 2, x = u & 3;
    int i = t / 14, j = t % 14;
    bool valid = (t < 196);
    if (x == 0) {
        float C0 = 0.f, S0 = 0.f;
        if (valid) { C0 = pos_logit(pos, w, b, 0, 2*i, 2*j); S0 = sp_fast(C0); }
        tbl[t*8 + 0] = C0; tbl[t*8 + 1] = S0;
    } else if (x == 1) {
        tbl[t*8 + 2] = valid ? pos_logit(pos, w, b, 1, 2*i+1, 2*j+1) : 0.f;
        tbl[t*8 + 5] = 0.f;
    } else if (x == 2) {
        tbl[t*8 + 3] = valid ? pos_logit(pos, w, b, 2, 2*i,   2*j+1) : 0.f;
        tbl[t*8 + 6] = 0.f;
    } else {
        tbl[t*8 + 4] = valid ? pos_logit(pos, w, b, 3, 2*i+1, 2*j) : 0.f;
        tbl[t*8 + 7] = 0.f;
    }
}

__global__ __launch_bounds__(256, 4)
void main_kernel(const float* __restrict__ samples,
                 const float* __restrict__ w,
                 const float* __restrict__ tbl,
                 float* __restrict__ partial) {
    // wave-private 4 parity planes, 16x16 each (1-elem zero halo all around).
    // No __syncthreads anywhere: each wave reads/writes only planes[wv], and
    // same-wave DS ops execute in order; wave_barrier() pins compiler order.
    __shared__ float planes[4][1024];   // 16 KB
    const int tid = threadIdx.x;
    const int wv = tid >> 6, ln = tid & 63;
    float* myP = planes[wv];

    // sample-channel tap weights: weights[x][0][0][ky][kx] = w[x*18 + ky*3 + kx]
    const float w1a = w[18+0], w1b = w[18+2], w1c = w[18+6], w1d = w[18+8]; // b1 corners
    const float w2l = w[36+3], w2r = w[36+5], w2u = w[36+1], w2n = w[36+7]; // b2
    const float w3u = w[54+1], w3n = w[54+7], w3l = w[54+3], w3r = w[54+5]; // b3 a/d
    const float w3a = w[54+0], w3b = w[54+2], w3c = w[54+6], w3e = w[54+8]; // b3 corner b

    // per-lane quad tables (quads t = k*64 + lane) from ws
    float C0[4], P1[4], P2[4], P3[4], S0s = 0.f;
    int oq[4], wo[4]; bool qv[4];
    #pragma unroll
    for (int k = 0; k < 4; ++k) {
        int t = k*64 + ln;
        qv[k] = (t < 196);
        int i = t / 14, j = t - 14*i;
        oq[k] = (i+1)*16 + (j+1);
        const float4* t4 = (const float4*)(tbl + t*8);
        float4 lo = t4[0], hi = t4[1];
        C0[k] = lo.x; S0s += lo.y; P1[k] = lo.z; P2[k] = lo.w; P3[k] = hi.x;
        // float4 g covers row r=g/7, cols 4m..4m+3 -> parity de-interleave target
        int r = t / 7, m = t - 7*r;
        wo[k] = ((r & 1) ? 512 : 0) + ((r >> 1) + 1)*16 + 2*m + 1;
    }

    // zero own planes once (halo stays zero; interior rewritten per image)
    #pragma unroll
    for (int z = 0; z < 4; ++z)
        ((float4*)myP)[z*64 + ln] = float4{0.f, 0.f, 0.f, 0.f};

    // branch-0 softplus term is image-independent: fold both images out
    float acc = -2.0f * S0s;
    const int img0 = blockIdx.x * 8 + wv * 2;

    #pragma unroll
    for (int im = 0; im < 2; ++im) {
        const float4* src = (const float4*)(samples + (size_t)(img0 + im) * 784);
        float4 v[4];
        #pragma unroll
        for (int k = 0; k < 4; ++k)
            if (k < 3 || ln < 4) v[k] = src[k*64 + ln];   // 196 = 3*64 + 4
        __builtin_amdgcn_wave_barrier();    // prior image's reads stay before these writes
        #pragma unroll
        for (int k = 0; k < 4; ++k)
            if (k < 3 || ln < 4) {
                float* p = myP + wo[k];
                p[0]   = v[k].x;  p[256] = v[k].y;   // a/c , b/d de-interleave
                p[1]   = v[k].z;  p[257] = v[k].w;
            }
        __builtin_amdgcn_wave_barrier();    // writes stay before reads
        #pragma unroll
        for (int k = 0; k < 4; ++k) {
            if (qv[k]) {
                const int o = oq[k];
                float a00 = myP[o],        a01 = myP[o+1];
                float a10 = myP[o+16],     a11 = myP[o+17];
                float bl  = myP[256+o-1],  bij = myP[256+o];
                float bdl = myP[256+o+15], bdn = myP[256+o+16];
                float cij = myP[512+o];
                float dup = myP[768+o-16], dl  = myP[768+o-1], dij = myP[768+o];

                // branch 0 (pixel a): logit = C0 const; softplus already folded
                acc = fmaf(a00, C0[k], acc);
                // branch 1 (pixel d): 4 a-corners
                float L1 = P1[k];
                L1 = fmaf(w1a, a00, L1); L1 = fmaf(w1b, a01, L1);
                L1 = fmaf(w1c, a10, L1); L1 = fmaf(w1d, a11, L1);
                acc += fmaf(dij, L1, -sp_fast(L1));
                // branch 2 (pixel b): horiz a, vert d
                float L2 = P2[k];
                L2 = fmaf(w2l, a00, L2); L2 = fmaf(w2r, a01, L2);
                L2 = fmaf(w2u, dup, L2); L2 = fmaf(w2n, dij, L2);
                acc += fmaf(bij, L2, -sp_fast(L2));
                // branch 3 (pixel c): vert a, horiz d, corner b
                float L3 = P3[k];
                L3 = fmaf(w3u, a00, L3); L3 = fmaf(w3n, a10, L3);
                L3 = fmaf(w3l, dl,  L3); L3 = fmaf(w3r, dij, L3);
                L3 = fmaf(w3a, bl,  L3); L3 = fmaf(w3b, bij, L3);
                L3 = fmaf(w3c, bdl, L3); L3 = fmaf(w3e, bdn, L3);
                acc += fmaf(cij, L3, -sp_fast(L3));
            }
        }
    }

    // wave butterfly -> one plain store per wave (no atomics, no barrier)
    #pragma unroll
    for (int off = 32; off >= 1; off >>= 1)
        acc += __shfl_xor(acc, off, 64);
    if (ln == 0) partial[blockIdx.x * 4 + wv] = acc;
}

// reduce 8192 per-wave partials -> out[0]; overwrites the 0xAA poison directly
__global__ void final_kernel(const float* __restrict__ partial,
                             float* __restrict__ out) {
    __shared__ float red[4];
    const int tid = threadIdx.x;
    float s = 0.f;
    #pragma unroll
    for (int i = 0; i < 32; ++i) s += partial[i*256 + tid];
    #pragma unroll
    for (int off = 32; off >= 1; off >>= 1) s += __shfl_xor(s, off, 64);
    if ((tid & 63) == 0) red[tid >> 6] = s;
    __syncthreads();
    if (tid == 0) out[0] = red[0] + red[1] + red[2] + red[3];
}

extern "C" void kernel_launch(void* const* d_in, const int* in_sizes, int n_in,
                              void* d_out, int out_size, void* d_ws, size_t ws_size,
                              hipStream_t stream) {
    const float* samples  = (const float*)d_in[0];
    const float* position = (const float*)d_in[1];
    const float* weights  = (const float*)d_in[2];
    const float* biases   = (const float*)d_in[3];
    float* ws_f = (float*)d_ws;
    float* tbl     = ws_f;          // 1568 floats
    float* partial = ws_f + 2048;   // 8192 floats
    float* out = (float*)d_out;

    prep_kernel<<<4, 256, 0, stream>>>(position, weights, biases, tbl);
    main_kernel<<<GRID, 256, 0, stream>>>(samples, weights, tbl, partial);
    final_kernel<<<1, 256, 0, stream>>>(partial, out);
}